// Round 1
// 561.801 us; speedup vs baseline: 1.0065x; 1.0065x over previous
//
#include <hip/hip_runtime.h>
#include <math.h>

// N=16384, D=4096, E=256, TOPK=6, scale=1.5
constexpr int D     = 4096;
constexpr int D4    = 1024;     // float4 per row
constexpr int E     = 256;
constexpr int TK    = 6;
constexpr int BM    = 64;       // rows per block
constexpr int NT    = 512;      // 8 waves
constexpr int NTILE = 128;      // D / 32
constexpr float TAU = 3e-5f;    // ambiguity threshold

typedef __attribute__((ext_vector_type(8)))  short short8;
typedef __attribute__((ext_vector_type(16))) float float16;
typedef unsigned short ushort_t;

#define GAS __attribute__((address_space(1)))
#define LAS __attribute__((address_space(3)))

__device__ __forceinline__ ushort_t f2bf(float f) {  // RTNE fp32->bf16
  unsigned u = __float_as_uint(f);
  return (ushort_t)((u + 0x7fffu + ((u >> 16) & 1u)) >> 16);
}
__device__ __forceinline__ float bf2f(ushort_t h) {
  return __uint_as_float(((unsigned)h) << 16);
}
__device__ __forceinline__ int swz4(int r) { return (r & 3) ^ ((r >> 2) & 3); }

// async 16B global -> LDS (lds dest = uniform base + lane*16)
__device__ __forceinline__ void gload_lds16(const ushort_t* g, ushort_t* l) {
  __builtin_amdgcn_global_load_lds((const GAS unsigned int*)g,
                                   (LAS unsigned int*)l, 16, 0, 0);
}

// Wave-private B staging: wave w owns experts [32w, 32w+32) for ALL 64 rows.
// B sync = counted vmcnt only (no barrier). A (x rows) is cooperative,
// double-buffered, raw s_barrier + lgkmcnt(0) (vmcnt NOT drained).
struct __align__(16) SMem {
  union {
    struct {                     // 144 KB staging
      ushort_t Bh[4][8][32 * 32];   // [buf][wave][expert*32+k]
      ushort_t Bl[4][8][32 * 32];
      ushort_t Ah[2][BM * 32];
      ushort_t Al[2][BM * 32];
    } st;
    struct {                     // merge buffer (staging dead by then)
      float val[BM * 65];        // 8 groups x 8 candidates per row
      int   id [BM * 65];
    } mg;
  } u;
  float  bias[E];
  int    nflag;
  int    flagrow[BM];
  int    flagid[BM][8];
  double exact[8];
};
static_assert(sizeof(SMem) <= 160 * 1024, "LDS overflow");

// ---------- prepass: W fp32 -> bf16 hi/lo in workspace ----------
__global__ __launch_bounds__(256)
void conv_w(const float* __restrict__ wg, ushort_t* __restrict__ whi,
            ushort_t* __restrict__ wlo)
{
  size_t i = (size_t)blockIdx.x * 256 + threadIdx.x;   // over E*D/4
  float4 v = ((const float4*)wg)[i];
  float a[4] = {v.x, v.y, v.z, v.w};
  ushort_t h[4], l[4];
#pragma unroll
  for (int j = 0; j < 4; ++j) {
    h[j] = f2bf(a[j]);
    l[j] = f2bf(a[j] - bf2f(h[j]));
  }
  *(uint2*)&whi[i * 4] = *(uint2*)h;
  *(uint2*)&wlo[i * 4] = *(uint2*)l;
}

#define WAITV5   asm volatile("s_waitcnt vmcnt(5)" ::: "memory")
#define WAITV0   asm volatile("s_waitcnt vmcnt(0)" ::: "memory")
#define LGKM0    asm volatile("s_waitcnt lgkmcnt(0)" ::: "memory")
#define MEMFENCE asm volatile("" ::: "memory")

// ---------- main fused kernel ----------
__global__ __launch_bounds__(NT, 2)
void gate_kernel(const float* __restrict__ xg, const float* __restrict__ wg,
                 const float* __restrict__ bg,
                 const ushort_t* __restrict__ whi, const ushort_t* __restrict__ wlo,
                 float* __restrict__ outw, float* __restrict__ outi)
{
  __shared__ SMem sm;
  const int t    = threadIdx.x;
  const int row0 = blockIdx.x * BM;
  const int wv   = t >> 6;       // wave 0..7 -> experts [32wv, 32wv+32)
  const int lane = t & 63;
  const int m    = lane & 31;
  const int hf   = lane >> 5;

  if (t < E) sm.bias[t] = bg[t];
  if (t == 0) sm.nflag = 0;

  const float4* x4 = (const float4*)xg;
  const float4* w4 = (const float4*)wg;

  float16 acc0, acc1;            // rows 0-31 / rows 32-63 x experts of wave
#pragma unroll
  for (int i = 0; i < 16; ++i) { acc0[i] = 0.f; acc1[i] = 0.f; }

  // A staging roles: 1 float4/thread per tile
  const int a_row = t >> 3;      // 0..63
  const int a_c   = t & 7;       // f4 column within 32-wide k slice

  // B staging roles: lane -> (expert-in-16-group, 16B chunk)
  const int e16 = lane >> 2;     // 0..15
  const int ch  = lane & 3;

  const int sA = swz4(m);

  auto stage_B = [&](int kt, int p) {
#pragma unroll
    for (int j = 0; j < 2; ++j) {
      const int er = j * 16 + e16;                       // expert rel 0..31
      const int cs = ch ^ swz4(er);                      // swizzled src chunk
      const size_t go = (size_t)(wv * 32 + er) * D + kt * 32 + cs * 8;
      gload_lds16(whi + go, &sm.u.st.Bh[p][wv][j * 512]);
      gload_lds16(wlo + go, &sm.u.st.Bl[p][wv][j * 512]);
    }
  };
  auto store_A = [&](int p, float4 xv) {
    float av[4] = {xv.x, xv.y, xv.z, xv.w};
    ushort_t h[4], l[4];
#pragma unroll
    for (int i = 0; i < 4; ++i) {
      h[i] = f2bf(av[i]);
      l[i] = f2bf(av[i] - bf2f(h[i]));
    }
    const int c  = a_c >> 1, hh = a_c & 1;
    const int sl = (c ^ swz4(a_row)) * 8 + hh * 4;
    *(uint2*)&sm.u.st.Ah[p][a_row * 32 + sl] = *(uint2*)h;
    *(uint2*)&sm.u.st.Al[p][a_row * 32 + sl] = *(uint2*)l;
  };
  auto compute = [&](int pa, int pb) {
#pragma unroll
    for (int ks = 0; ks < 2; ++ks) {
      const int sl = ((2 * ks + hf) ^ sA) * 8;
      short8 a0h = *(const short8*)&sm.u.st.Ah[pa][m * 32 + sl];
      short8 a0l = *(const short8*)&sm.u.st.Al[pa][m * 32 + sl];
      short8 a1h = *(const short8*)&sm.u.st.Ah[pa][(32 + m) * 32 + sl];
      short8 a1l = *(const short8*)&sm.u.st.Al[pa][(32 + m) * 32 + sl];
      short8 bh  = *(const short8*)&sm.u.st.Bh[pb][wv][m * 32 + sl];
      short8 bl  = *(const short8*)&sm.u.st.Bl[pb][wv][m * 32 + sl];
      acc0 = __builtin_amdgcn_mfma_f32_32x32x16_bf16(a0h, bh, acc0, 0, 0, 0);
      acc0 = __builtin_amdgcn_mfma_f32_32x32x16_bf16(a0h, bl, acc0, 0, 0, 0);
      acc0 = __builtin_amdgcn_mfma_f32_32x32x16_bf16(a0l, bh, acc0, 0, 0, 0);
      acc1 = __builtin_amdgcn_mfma_f32_32x32x16_bf16(a1h, bh, acc1, 0, 0, 0);
      acc1 = __builtin_amdgcn_mfma_f32_32x32x16_bf16(a1h, bl, acc1, 0, 0, 0);
      acc1 = __builtin_amdgcn_mfma_f32_32x32x16_bf16(a1l, bh, acc1, 0, 0, 0);
    }
  };

  // ---- prologue: prime depth-2 pipeline (5 VMEM ops per tile, uniform) ----
  float4 x0 = x4[(size_t)(row0 + a_row) * D4 + 0 * 8 + a_c];
  float4 xA = x4[(size_t)(row0 + a_row) * D4 + 1 * 8 + a_c];
  stage_B(0, 0);
  WAITV5;                        // x0 landed (xA, B0 may be in flight)
  store_A(0, x0);
  float4 xB = x4[(size_t)(row0 + a_row) * D4 + 2 * 8 + a_c];
  stage_B(1, 1);
  LGKM0;
  __builtin_amdgcn_s_barrier();
  MEMFENCE;

  // ---- K loop: vmcnt(5) gives every load a 2-tile latency budget; raw
  // barrier (no vmcnt drain) only for the cross-wave A handoff ----
#define TILE_BODY(KT, XS)                                                     \
  do {                                                                        \
    const int P   = (KT) & 3;                                                 \
    const int PW  = ((KT) + 2) & 3;                                           \
    const int PA  = (KT) & 1;                                                 \
    const int PA1 = ((KT) + 1) & 1;                                           \
    WAITV5;                         /* completes x(KT+1) and B(KT) */         \
    store_A(PA1, XS);                                                         \
    { const int kl = ((KT) + 3 < NTILE) ? (KT) + 3 : NTILE - 1;               \
      XS = x4[(size_t)(row0 + a_row) * D4 + kl * 8 + a_c]; }                  \
    { const int kb = ((KT) + 2 < NTILE) ? (KT) + 2 : NTILE - 1;               \
      stage_B(kb, PW); }                                                      \
    compute(PA, P);                                                           \
    LGKM0;                          /* A writes visible; vmcnt stays loaded */\
    __builtin_amdgcn_s_barrier();                                             \
    MEMFENCE;                                                                 \
  } while (0)

  for (int it = 0; it < NTILE / 4; ++it) {
    const int kt = it * 4;
    TILE_BODY(kt + 0, xA);
    TILE_BODY(kt + 1, xB);
    TILE_BODY(kt + 2, xA);
    TILE_BODY(kt + 3, xB);
  }
#undef TILE_BODY

  // drain tail garbage global_load_lds before reusing the union as merge buf
  WAITV0;
  __syncthreads();

  // ---- per-wave top-8 over this wave's 32 experts, per row ----
  const int eBase  = wv * 32;
  const int myE    = eBase + m;
  const float myBias = sm.bias[myE];

#pragma unroll
  for (int b = 0; b < 2; ++b) {
#pragma unroll
    for (int reg = 0; reg < 16; ++reg) {
      const int row_local = b * 32 + (reg & 3) + 8 * (reg >> 2) + 4 * hf;
      float s = b ? acc1[reg] : acc0[reg];
      float v = sqrtf(fmaxf(s, 0.f) + log1pf(expf(-fabsf(s)))) + myBias;
#pragma unroll
      for (int ssel = 0; ssel < 8; ++ssel) {
        float bv = v;
#pragma unroll
        for (int off = 1; off < 32; off <<= 1)
          bv = fmaxf(bv, __shfl_xor(bv, off, 64));
        unsigned long long ball = __ballot(v == bv);
        unsigned hm = (unsigned)(ball >> (hf * 32));
        int mwin = __ffs(hm) - 1;            // lowest expert wins ties
        if (m == mwin) {
          sm.u.mg.val[row_local * 65 + wv * 8 + ssel] = v;
          sm.u.mg.id [row_local * 65 + wv * 8 + ssel] = myE;
          v = -INFINITY;
        }
      }
    }
  }
  __syncthreads();

  // ---- merge 8x8 -> global top-8 per row; flag ambiguous rows ----
  {
    const int r = t >> 3, g = t & 7;
    float mv[8]; int mi[8];
#pragma unroll
    for (int q = 0; q < 8; ++q) {
      mv[q] = sm.u.mg.val[r * 65 + q * 8 + g];
      mi[q] = sm.u.mg.id [r * 65 + q * 8 + g];
    }
    float tv[8]; int ti[8];
#pragma unroll
    for (int s = 0; s < 8; ++s) {
      float bv = mv[0]; int bi = mi[0];
#pragma unroll
      for (int q = 1; q < 8; ++q)
        if (mv[q] > bv || (mv[q] == bv && mi[q] < bi)) { bv = mv[q]; bi = mi[q]; }
#pragma unroll
      for (int off = 1; off < 8; off <<= 1) {
        float ov = __shfl_xor(bv, off, 64);
        int   oi = __shfl_xor(bi, off, 64);
        if (ov > bv || (ov == bv && oi < bi)) { bv = ov; bi = oi; }
      }
      tv[s] = bv; ti[s] = bi;
#pragma unroll
      for (int q = 0; q < 8; ++q)
        if (mi[q] == bi) mv[q] = -INFINITY;
    }
    if (g == 0) {
      bool flag = false;
#pragma unroll
      for (int i = 0; i < 7; ++i) flag |= (tv[i] - tv[i + 1] < TAU);
      const int grow = row0 + r;
      if (!flag) {
        float og[6], ssum = 0.f;
#pragma unroll
        for (int i = 0; i < 6; ++i) { og[i] = tv[i] - sm.bias[ti[i]]; ssum += og[i]; }
        const float sc = 1.5f / ssum;
#pragma unroll
        for (int i = 0; i < 6; ++i) {
          outw[(size_t)grow * TK + i] = og[i] * sc;
          outi[(size_t)grow * TK + i] = (float)ti[i];
        }
      } else {
        int slot = atomicAdd(&sm.nflag, 1);
        sm.flagrow[slot] = grow;
#pragma unroll
        for (int i = 0; i < 8; ++i) sm.flagid[slot][i] = ti[i];
      }
    }
  }
  __syncthreads();

  // ---- exact fp64 rescue for flagged rows (expected <1/block) ----
  const int nf = sm.nflag;
  for (int f = 0; f < nf; ++f) {
    const int grow = sm.flagrow[f];
    const int e    = sm.flagid[f][wv];
    double accd = 0.0;
    const float4* xr = x4 + (size_t)grow * D4 + lane * 16;
    const float4* wr = w4 + (size_t)e    * D4 + lane * 16;
#pragma unroll
    for (int i = 0; i < 16; ++i) {
      float4 xv = xr[i], wl = wr[i];
      accd = fma((double)xv.x, (double)wl.x, accd);
      accd = fma((double)xv.y, (double)wl.y, accd);
      accd = fma((double)xv.z, (double)wl.z, accd);
      accd = fma((double)xv.w, (double)wl.w, accd);
    }
#pragma unroll
    for (int off = 1; off < 64; off <<= 1)
      accd += __shfl_xor(accd, off, 64);
    if (lane == 0) {
      double sp = fmax(accd, 0.0) + log1p(exp(-fabs(accd)));
      sm.exact[wv] = sqrt(sp);   // orig (unbiased) score
    }
    __syncthreads();
    if (t == 0) {
      double ov[8]; int oid[8], ordr[8];
      for (int i = 0; i < 8; ++i) { ov[i] = sm.exact[i]; oid[i] = sm.flagid[f][i]; ordr[i] = i; }
      for (int i = 0; i < 6; ++i) {
        int b = i;
        for (int j = i + 1; j < 8; ++j) {
          double bj = ov[ordr[j]] + (double)sm.bias[oid[ordr[j]]];
          double bb = ov[ordr[b]] + (double)sm.bias[oid[ordr[b]]];
          if (bj > bb || (bj == bb && oid[ordr[j]] < oid[ordr[b]])) b = j;
        }
        int tmp = ordr[i]; ordr[i] = ordr[b]; ordr[b] = tmp;
      }
      double ssum = 0.0;
      for (int i = 0; i < 6; ++i) ssum += ov[ordr[i]];
      double sc = 1.5 / ssum;
      for (int i = 0; i < 6; ++i) {
        outw[(size_t)grow * TK + i] = (float)(ov[ordr[i]] * sc);
        outi[(size_t)grow * TK + i] = (float)oid[ordr[i]];
      }
    }
    __syncthreads();
  }
}

extern "C" void kernel_launch(void* const* d_in, const int* in_sizes, int n_in,
                              void* d_out, int out_size, void* d_ws, size_t ws_size,
                              hipStream_t stream) {
  const float* x = (const float*)d_in[0];
  const float* w = (const float*)d_in[1];
  const float* b = (const float*)d_in[2];
  float* out  = (float*)d_out;
  const int N = in_sizes[0] / D;          // 16384

  ushort_t* whi = (ushort_t*)d_ws;                      // E*D bf16 = 2 MB
  ushort_t* wlo = whi + (size_t)E * D;                  // +2 MB

  float* outw = out;                      // [N,6] weights
  float* outi = out + (size_t)N * TK;     // [N,6] indices (as float)

  hipLaunchKernelGGL(conv_w, dim3(E * D / 4 / 256), dim3(256), 0, stream,
                     w, whi, wlo);
  hipLaunchKernelGGL(gate_kernel, dim3(N / BM), dim3(NT), 0, stream,
                     x, w, b, whi, wlo, outw, outi);
}